// Round 4
// baseline (498.309 us; speedup 1.0000x reference)
//
#include <hip/hip_runtime.h>
#include <hip/hip_bf16.h>

#define DEVI __device__ __forceinline__

typedef __attribute__((ext_vector_type(8))) short bf16x8;
typedef __attribute__((ext_vector_type(4))) float f32x4;
typedef unsigned short u16;

static constexpr float SCALE = 0.03125f;             // 1/sqrt(1024)
static constexpr float C2 = 0.045084220045134115f;   // SCALE * log2(e)

// fast RNE f32->bf16 (no NaN path; all values finite here)
DEVI u16 f2bf_rne(float f){
    unsigned t = __builtin_bit_cast(unsigned, f);
    t += 0x7fffu + ((t >> 16) & 1u);
    return (u16)(t >> 16);
}
// RNE pack of two f32 -> u32 (lo in [15:0], hi in [31:16]).
// NOTE: v_cvt_pk_bf16_f32 is NOT RNE on gfx950 (R3 failed with it: absmax 2.2e-3) — do not use.
DEVI unsigned pack_bf16_rne(float lo, float hi){
    return (unsigned)f2bf_rne(lo) | ((unsigned)f2bf_rne(hi) << 16);
}
DEVI float exp2_hw(float x){
#if defined(__has_builtin) && __has_builtin(__builtin_amdgcn_exp2f)
    return __builtin_amdgcn_exp2f(x);
#else
    return __expf(x * 0.6931471805599453f);
#endif
}

DEVI void gload16(const void* g, void* l){
    __builtin_amdgcn_global_load_lds(
        (const __attribute__((address_space(1))) void*)g,
        (__attribute__((address_space(3))) void*)l,
        16, 0, 0);
}

DEVI void plswap32(unsigned &a, unsigned &b){
#if defined(__has_builtin) && __has_builtin(__builtin_amdgcn_permlane32_swap)
    typedef unsigned uv2 __attribute__((ext_vector_type(2)));
    uv2 r = __builtin_amdgcn_permlane32_swap(a, b, false, false);
    a = r[0]; b = r[1];
#else
    asm("v_permlane32_swap_b32 %0, %1" : "+v"(a), "+v"(b));
#endif
}
DEVI void plswap16(unsigned &a, unsigned &b){
#if defined(__has_builtin) && __has_builtin(__builtin_amdgcn_permlane16_swap)
    typedef unsigned uv2 __attribute__((ext_vector_type(2)));
    uv2 r = __builtin_amdgcn_permlane16_swap(a, b, false, false);
    a = r[0]; b = r[1];
#else
    asm("v_permlane16_swap_b32 %0, %1" : "+v"(a), "+v"(b));
#endif
}

// ---------------- fp32 -> bf16 bulk convert ----------------
__global__ __launch_bounds__(256) void k_cvt(const float* __restrict__ src,
                                             u16* __restrict__ dst, int n8){
    int stride = gridDim.x * blockDim.x;
    for (int i = blockIdx.x * blockDim.x + threadIdx.x; i < n8; i += stride){
        float4 a = *(const float4*)(src + (size_t)i*8);
        float4 b = *(const float4*)(src + (size_t)i*8 + 4);
        uint4 o;
        o.x = pack_bf16_rne(a.x, a.y);
        o.y = pack_bf16_rne(a.z, a.w);
        o.z = pack_bf16_rne(b.x, b.y);
        o.w = pack_bf16_rne(b.z, b.w);
        *(uint4*)(dst + (size_t)i*8) = o;
    }
}

// ---------------- 128x128 NT GEMM, C = A * B^T ----------------
// EPI 0: fp32 store. EPI 1: QKV scatter -> qh/kh (head-split) + vT (transposed, 8B packed).
template<int EPI>
__global__ __launch_bounds__(256) void k_gemm(
    const u16* __restrict__ A, const u16* __restrict__ Bm,
    float* __restrict__ Cf, u16* __restrict__ qh, u16* __restrict__ kh, u16* __restrict__ vT,
    int K, int N)
{
    __shared__ __align__(16) u16 As[128*32];
    __shared__ __align__(16) u16 Bs[128*32];
    const int lane = threadIdx.x & 63, wid = threadIdx.x >> 6;

    const int nbx = gridDim.x;
    const int nwg = nbx * gridDim.y;
    const int bid = blockIdx.y * nbx + blockIdx.x;
    const int swz = (bid & 7) * (nwg >> 3) + (bid >> 3);
    const int rowTile = (swz / nbx) * 128;
    const int colTile = (swz % nbx) * 128;

    const int wr = wid >> 1, wc = wid & 1;
    const int lrow = lane >> 2, lch = lane & 3;

    f32x4 acc[4][4] = {};

    for (int k0 = 0; k0 < K; k0 += 32){
        __syncthreads();
        #pragma unroll
        for (int cc = 0; cc < 2; ++cc){
            int c = wid*2 + cc;
            int row = c*16 + lrow;
            gload16(A + (size_t)(rowTile + row)*K + k0 + lch*8, (char*)As + c*1024);
            gload16(Bm + (size_t)(colTile + row)*K + k0 + lch*8, (char*)Bs + c*1024);
        }
        __syncthreads();
        bf16x8 af[4], bfr[4];
        #pragma unroll
        for (int mi = 0; mi < 4; ++mi){
            int row = wr*64 + mi*16 + (lane & 15);
            af[mi] = *(const bf16x8*)((const char*)As + row*64 + (lane>>4)*16);
        }
        #pragma unroll
        for (int nj = 0; nj < 4; ++nj){
            int row = wc*64 + nj*16 + (lane & 15);
            bfr[nj] = *(const bf16x8*)((const char*)Bs + row*64 + (lane>>4)*16);
        }
        #pragma unroll
        for (int mi = 0; mi < 4; ++mi)
            #pragma unroll
            for (int nj = 0; nj < 4; ++nj)
                acc[mi][nj] = __builtin_amdgcn_mfma_f32_16x16x32_bf16(af[mi], bfr[nj], acc[mi][nj], 0,0,0);
    }

    #pragma unroll
    for (int mi = 0; mi < 4; ++mi)
        #pragma unroll
        for (int nj = 0; nj < 4; ++nj){
            int row0 = rowTile + wr*64 + mi*16 + (lane>>4)*4;
            int col  = colTile + wc*64 + nj*16 + (lane & 15);
            if (EPI == 0){
                #pragma unroll
                for (int j = 0; j < 4; ++j)
                    Cf[(size_t)(row0+j)*N + col] = acc[mi][nj][j];
            } else {
                int b = row0 >> 11, srow0 = row0 & 2047;
                if (col < 2048){
                    u16* dst = (col < 1024) ? qh : kh;
                    int c2 = col & 1023; int h = c2 >> 6, dh = c2 & 63;
                    size_t base = ((size_t)((b<<4)+h)*2048 + srow0)*64 + dh;
                    #pragma unroll
                    for (int j = 0; j < 4; ++j)
                        dst[base + (size_t)j*64] = f2bf_rne(acc[mi][nj][j]);
                } else {
                    int c2 = col - 2048; int h = c2 >> 6, dh = c2 & 63;
                    union { u16 s[4]; uint2 u; } p;
                    #pragma unroll
                    for (int j = 0; j < 4; ++j) p.s[j] = f2bf_rne(acc[mi][nj][j]);
                    *(uint2*)(vT + ((size_t)((b<<4)+h)*64 + dh)*2048 + srow0) = p.u;
                }
            }
        }
}

// ---------------- Pass A+V: Z[k] = sum_q exp(S*k.q); then vT *= 1/Z in place ----------------
// grid (16 kblocks, 64 heads), 256 thr. Wave w owns k rows [w*32, w*32+32).
__global__ __launch_bounds__(256) void k_passAV(
    const u16* __restrict__ qh, const u16* __restrict__ kh, u16* __restrict__ vT)
{
    __shared__ __align__(16) u16 k_lds[128*64];
    __shared__ __align__(16) u16 q_lds[128*64];
    const int lane = threadIdx.x & 63, wid = threadIdx.x >> 6;
    const int kb = blockIdx.x, bh = blockIdx.y;

    // stage k block once (pre-swizzled source, linear LDS dest)
    #pragma unroll
    for (int cc = 0; cc < 4; ++cc){
        int c = wid*4 + cc;
        int row = c*8 + (lane>>3);
        int inner = (lane&7)*16;
        gload16((const char*)(kh + ((size_t)bh*2048 + kb*128 + row)*64) + (inner ^ ((row&7)<<4)),
                (char*)k_lds + c*1024);
    }

    uint4 pq[4];
    auto LOADQ = [&](int qt){
        #pragma unroll
        for (int cc = 0; cc < 4; ++cc){
            int c = wid*4 + cc;
            int row = c*8 + (lane>>3);
            pq[cc] = *(const uint4*)(qh + ((size_t)bh*2048 + qt*128 + row)*64 + (lane&7)*8);
        }
    };
    auto WRITEQ = [&](){
        #pragma unroll
        for (int cc = 0; cc < 4; ++cc){
            int c = wid*4 + cc;
            int row = c*8 + (lane>>3);
            *(uint4*)((char*)q_lds + row*128 + (((lane&7)*16) ^ ((row&7)<<4))) = pq[cc];
        }
    };

    LOADQ(0); WRITEQ();
    __syncthreads();     // k_lds (gload) + q_lds(0) visible

    f32x4 sums[2] = {};
    bf16x8 ak[2][2];

    for (int qt = 0; qt < 16; ++qt){
        if (qt < 15) LOADQ(qt+1);
        if (qt == 0){
            #pragma unroll
            for (int mi = 0; mi < 2; ++mi)
                #pragma unroll
                for (int kk = 0; kk < 2; ++kk){
                    int row = wid*32 + mi*16 + (lane & 15);
                    ak[mi][kk] = *(const bf16x8*)((const char*)k_lds + row*128
                                  + ((kk*64 + (lane>>4)*16) ^ ((row&7)<<4)));
                }
        }
        #pragma unroll
        for (int nj = 0; nj < 8; ++nj){
            int row = nj*16 + (lane & 15);
            int base = row*128, sw = (row&7)<<4;
            bf16x8 bq0 = *(const bf16x8*)((const char*)q_lds + base + (((lane>>4)*16) ^ sw));
            bf16x8 bq1 = *(const bf16x8*)((const char*)q_lds + base + ((64 + (lane>>4)*16) ^ sw));
            #pragma unroll
            for (int mi = 0; mi < 2; ++mi){
                f32x4 z = {};
                z = __builtin_amdgcn_mfma_f32_16x16x32_bf16(ak[mi][0], bq0, z, 0,0,0);
                z = __builtin_amdgcn_mfma_f32_16x16x32_bf16(ak[mi][1], bq1, z, 0,0,0);
                #pragma unroll
                for (int j = 0; j < 4; ++j) sums[mi][j] += exp2_hw(z[j] * C2);
            }
        }
        __syncthreads();
        if (qt < 15) WRITEQ();
        __syncthreads();
    }

    // per-k reciprocal denominators -> LDS (k_lds reused; dead since qt==0)
    float* rz_lds = (float*)k_lds;
    #pragma unroll
    for (int mi = 0; mi < 2; ++mi)
        #pragma unroll
        for (int j = 0; j < 4; ++j){
            float v = sums[mi][j];
            v += __shfl_xor(v, 1); v += __shfl_xor(v, 2);
            v += __shfl_xor(v, 4); v += __shfl_xor(v, 8);
            if ((lane & 15) == 0)
                rz_lds[wid*32 + mi*16 + (lane>>4)*4 + j] = 1.0f / v;
        }

    // stage this block's vT stripe [64 d][128 k] into q_lds (linear), scale, write back
    #pragma unroll
    for (int cc = 0; cc < 4; ++cc){
        int c = wid*4 + cc;
        int d = c*4 + (lane>>4);
        gload16(vT + ((size_t)bh*64 + d)*2048 + kb*128 + (lane&15)*8, (char*)q_lds + c*1024);
    }
    __syncthreads();   // rz_lds + v stage visible

    #pragma unroll
    for (int r = 0; r < 4; ++r){
        int ci = r*256 + threadIdx.x;       // 1024 chunks of 16B
        int d = ci >> 4, c = ci & 15;
        union { uint4 v; unsigned w[4]; } t;
        t.v = *(const uint4*)((const char*)q_lds + d*256 + c*16);
        #pragma unroll
        for (int m = 0; m < 4; ++m){
            float2 rzp = *(const float2*)&rz_lds[c*8 + m*2];
            float lo = __builtin_bit_cast(float, t.w[m] << 16) * rzp.x;
            float hi = __builtin_bit_cast(float, t.w[m] & 0xffff0000u) * rzp.y;
            t.w[m] = pack_bf16_rne(lo, hi);
        }
        *(uint4*)(vT + ((size_t)bh*64 + d)*2048 + kb*128 + c*8) = t.v;
    }
}

// ---------------- Pass B: out[q,d] = sum_k exp(S*q.k) * (v/Z)[k,d] ----------------
// Swapped QK^T -> P assembled into PV A-fragments in-register via permlane swaps.
__global__ __launch_bounds__(256) void k_passB(
    const u16* __restrict__ qh, const u16* __restrict__ kh, const u16* __restrict__ vT,
    u16* __restrict__ Zbf)
{
    __shared__ __align__(16) u16 q_lds[128*64];
    __shared__ __align__(16) u16 k_lds[128*64];
    __shared__ __align__(16) u16 v_lds[64*128];
    const int lane = threadIdx.x & 63, wid = threadIdx.x >> 6;
    const int qb = blockIdx.x, bh = blockIdx.y;

    // stage q block once (pre-swizzled source)
    #pragma unroll
    for (int cc = 0; cc < 4; ++cc){
        int c = wid*4 + cc;
        int row = c*8 + (lane>>3);
        int inner = (lane&7)*16;
        gload16((const char*)(qh + ((size_t)bh*2048 + qb*128 + row)*64) + (inner ^ ((row&7)<<4)),
                (char*)q_lds + c*1024);
    }

    uint4 pk[4], pv[4];
    auto LOADKV = [&](int kt){
        #pragma unroll
        for (int cc = 0; cc < 4; ++cc){
            int c = wid*4 + cc;
            int row = c*8 + (lane>>3);
            pk[cc] = *(const uint4*)(kh + ((size_t)bh*2048 + kt*128 + row)*64 + (lane&7)*8);
            int d = c*4 + (lane>>4);
            pv[cc] = *(const uint4*)(vT + ((size_t)bh*64 + d)*2048 + kt*128 + (lane&15)*8);
        }
    };
    auto WRITEKV = [&](){
        #pragma unroll
        for (int cc = 0; cc < 4; ++cc){
            int c = wid*4 + cc;
            int row = c*8 + (lane>>3);
            *(uint4*)((char*)k_lds + row*128 + (((lane&7)*16) ^ ((row&7)<<4))) = pk[cc];
            int d = c*4 + (lane>>4);
            *(uint4*)((char*)v_lds + d*256 + (((lane&15)*16) ^ ((d&7)<<4))) = pv[cc];
        }
    };

    LOADKV(0); WRITEKV();
    __syncthreads();

    f32x4 acc[2][4] = {};
    bf16x8 aq[2][2];

    for (int kt = 0; kt < 16; ++kt){
        if (kt < 15) LOADKV(kt+1);
        if (kt == 0){
            #pragma unroll
            for (int mi = 0; mi < 2; ++mi)
                #pragma unroll
                for (int kk = 0; kk < 2; ++kk){
                    int row = wid*32 + mi*16 + (lane & 15);
                    aq[mi][kk] = *(const bf16x8*)((const char*)q_lds + row*128
                                  + ((kk*64 + (lane>>4)*16) ^ ((row&7)<<4)));
                }
        }
        #pragma unroll
        for (int kk = 0; kk < 4; ++kk){
            bf16x8 bv[4];
            #pragma unroll
            for (int nj = 0; nj < 4; ++nj){
                int d = nj*16 + (lane & 15);
                bv[nj] = *(const bf16x8*)((const char*)v_lds + d*256
                           + ((kk*64 + (lane>>4)*16) ^ ((d&7)<<4)));
            }
            bf16x8 bkt[2][2];
            #pragma unroll
            for (int t = 0; t < 2; ++t){
                int row = (kk*2 + t)*16 + (lane & 15);
                int base = row*128, sw = (row&7)<<4;
                bkt[t][0] = *(const bf16x8*)((const char*)k_lds + base + (((lane>>4)*16) ^ sw));
                bkt[t][1] = *(const bf16x8*)((const char*)k_lds + base + ((64 + (lane>>4)*16) ^ sw));
            }
            #pragma unroll
            for (int mi = 0; mi < 2; ++mi){
                f32x4 z0 = {}, z1 = {};
                z0 = __builtin_amdgcn_mfma_f32_16x16x32_bf16(bkt[0][0], aq[mi][0], z0, 0,0,0);
                z0 = __builtin_amdgcn_mfma_f32_16x16x32_bf16(bkt[0][1], aq[mi][1], z0, 0,0,0);
                z1 = __builtin_amdgcn_mfma_f32_16x16x32_bf16(bkt[1][0], aq[mi][0], z1, 0,0,0);
                z1 = __builtin_amdgcn_mfma_f32_16x16x32_bf16(bkt[1][1], aq[mi][1], z1, 0,0,0);
                unsigned u0 = pack_bf16_rne(exp2_hw(z0[0]*C2), exp2_hw(z0[1]*C2));
                unsigned u1 = pack_bf16_rne(exp2_hw(z0[2]*C2), exp2_hw(z0[3]*C2));
                unsigned w0 = pack_bf16_rne(exp2_hw(z1[0]*C2), exp2_hw(z1[1]*C2));
                unsigned w1 = pack_bf16_rne(exp2_hw(z1[2]*C2), exp2_hw(z1[3]*C2));
                plswap32(u0, w0); plswap16(u0, w0);
                plswap32(u1, w1); plswap16(u1, w1);
                union { uint4 ui; bf16x8 v8; } ap;
                ap.ui.x = u0; ap.ui.y = u1; ap.ui.z = w0; ap.ui.w = w1;
                #pragma unroll
                for (int nj = 0; nj < 4; ++nj)
                    acc[mi][nj] = __builtin_amdgcn_mfma_f32_16x16x32_bf16(ap.v8, bv[nj], acc[mi][nj], 0,0,0);
            }
        }
        __syncthreads();
        if (kt < 15) WRITEKV();
        __syncthreads();
    }

    // epilogue -> merged-head bf16 [b*2048+q][h*64+d]
    const int b = bh >> 4, h = bh & 15;
    #pragma unroll
    for (int mi = 0; mi < 2; ++mi)
        #pragma unroll
        for (int nj = 0; nj < 4; ++nj)
            #pragma unroll
            for (int j = 0; j < 4; ++j){
                int qrow = qb*128 + wid*32 + mi*16 + (lane>>4)*4 + j;
                int d = nj*16 + (lane & 15);
                Zbf[((size_t)b*2048 + qrow)*1024 + h*64 + d] = f2bf_rne(acc[mi][nj][j]);
            }
}

extern "C" void kernel_launch(void* const* d_in, const int* in_sizes, int n_in,
                              void* d_out, int out_size, void* d_ws, size_t ws_size,
                              hipStream_t stream)
{
    const float* x  = (const float*)d_in[0];
    const float* Wq = (const float*)d_in[1];
    const float* Wk = (const float*)d_in[2];
    const float* Wv = (const float*)d_in[3];
    const float* Wo = (const float*)d_in[4];

    char* ws = (char*)d_ws;
    u16*   xbf  = (u16*)ws;                       // 16 MB; reused later as Zbf
    u16*   wqkv = (u16*)(ws + (16u<<20));         //  6 MB
    u16*   wobf = (u16*)(ws + (22u<<20));         //  2 MB
    u16*   vT   = (u16*)(ws + (24u<<20));         // 16 MB [64 bh][64 dh][2048 s]
    u16*   Zbf  = xbf;

    u16* qh = (u16*)d_out;                        // 16 MB [64 bh][2048 s][64 dh]
    u16* kh = (u16*)d_out + (size_t)8192*1024;    // 16 MB

    k_cvt<<<1024, 256, 0, stream>>>(x,  xbf,  8192*1024/8);
    k_cvt<<<256,  256, 0, stream>>>(Wq, wqkv,               1024*1024/8);
    k_cvt<<<256,  256, 0, stream>>>(Wk, wqkv + 1024*1024,   1024*1024/8);
    k_cvt<<<256,  256, 0, stream>>>(Wv, wqkv + 2*1024*1024, 1024*1024/8);
    k_cvt<<<256,  256, 0, stream>>>(Wo, wobf,               1024*1024/8);

    // QKV projection (fused): [8192][1024] x [3072][1024]^T
    k_gemm<1><<<dim3(24, 64), 256, 0, stream>>>(xbf, wqkv, nullptr, qh, kh, vT, 1024, 3072);

    // Pass A: per-key denominators + in-place V scaling
    k_passAV<<<dim3(16, 64), 256, 0, stream>>>(qh, kh, vT);

    // Pass B: fused QK^T -> exp -> PV
    k_passB<<<dim3(16, 64), 256, 0, stream>>>(qh, kh, vT, Zbf);

    // Output projection: [8192][1024] x [1024][1024]^T -> fp32 d_out
    k_gemm<0><<<dim3(8, 64), 256, 0, stream>>>(Zbf, wobf, (float*)d_out,
                                               nullptr, nullptr, nullptr, 1024, 1024);
}

// Round 5
// 362.348 us; speedup vs baseline: 1.3752x; 1.3752x over previous
//
#include <hip/hip_runtime.h>
#include <hip/hip_bf16.h>

#define DEVI __device__ __forceinline__

typedef __attribute__((ext_vector_type(8))) short bf16x8;
typedef __attribute__((ext_vector_type(4))) float f32x4;
typedef unsigned short u16;

static constexpr float SCALE = 0.03125f;             // 1/sqrt(1024)
static constexpr float C2 = 0.045084220045134115f;   // SCALE * log2(e)

// fast RNE f32->bf16 (no NaN path; all values finite here)
DEVI u16 f2bf_rne(float f){
    unsigned t = __builtin_bit_cast(unsigned, f);
    t += 0x7fffu + ((t >> 16) & 1u);
    return (u16)(t >> 16);
}
// RNE pack of two f32 -> u32. NOTE: v_cvt_pk_bf16_f32 is NOT RNE on gfx950 (R3: absmax 2.2e-3).
DEVI unsigned pack_bf16_rne(float lo, float hi){
    return (unsigned)f2bf_rne(lo) | ((unsigned)f2bf_rne(hi) << 16);
}
DEVI float exp2_hw(float x){
#if defined(__has_builtin) && __has_builtin(__builtin_amdgcn_exp2f)
    return __builtin_amdgcn_exp2f(x);
#else
    return __expf(x * 0.6931471805599453f);
#endif
}

DEVI void gload16(const void* g, void* l){
    __builtin_amdgcn_global_load_lds(
        (const __attribute__((address_space(1))) void*)g,
        (__attribute__((address_space(3))) void*)l,
        16, 0, 0);
}

DEVI void plswap32(unsigned &a, unsigned &b){
#if defined(__has_builtin) && __has_builtin(__builtin_amdgcn_permlane32_swap)
    typedef unsigned uv2 __attribute__((ext_vector_type(2)));
    uv2 r = __builtin_amdgcn_permlane32_swap(a, b, false, false);
    a = r[0]; b = r[1];
#else
    asm("v_permlane32_swap_b32 %0, %1" : "+v"(a), "+v"(b));
#endif
}
DEVI void plswap16(unsigned &a, unsigned &b){
#if defined(__has_builtin) && __has_builtin(__builtin_amdgcn_permlane16_swap)
    typedef unsigned uv2 __attribute__((ext_vector_type(2)));
    uv2 r = __builtin_amdgcn_permlane16_swap(a, b, false, false);
    a = r[0]; b = r[1];
#else
    asm("v_permlane16_swap_b32 %0, %1" : "+v"(a), "+v"(b));
#endif
}

// ---------------- fp32 -> bf16 bulk convert ----------------
__global__ __launch_bounds__(256) void k_cvt(const float* __restrict__ src,
                                             u16* __restrict__ dst, int n8){
    int stride = gridDim.x * blockDim.x;
    for (int i = blockIdx.x * blockDim.x + threadIdx.x; i < n8; i += stride){
        float4 a = *(const float4*)(src + (size_t)i*8);
        float4 b = *(const float4*)(src + (size_t)i*8 + 4);
        uint4 o;
        o.x = pack_bf16_rne(a.x, a.y);
        o.y = pack_bf16_rne(a.z, a.w);
        o.z = pack_bf16_rne(b.x, b.y);
        o.w = pack_bf16_rne(b.z, b.w);
        *(uint4*)(dst + (size_t)i*8) = o;
    }
}

// ---------------- 128x128 NT GEMM, C = A * B^T ----------------
// EPI 0: fp32 store. EPI 1: QKV scatter -> qh/kh (head-split) + vT (transposed, 8B packed).
template<int EPI>
__global__ __launch_bounds__(256) void k_gemm(
    const u16* __restrict__ A, const u16* __restrict__ Bm,
    float* __restrict__ Cf, u16* __restrict__ qh, u16* __restrict__ kh, u16* __restrict__ vT,
    int K, int N)
{
    __shared__ __align__(16) u16 As[128*32];
    __shared__ __align__(16) u16 Bs[128*32];
    const int lane = threadIdx.x & 63, wid = threadIdx.x >> 6;

    const int nbx = gridDim.x;
    const int nwg = nbx * gridDim.y;
    const int bid = blockIdx.y * nbx + blockIdx.x;
    const int swz = (bid & 7) * (nwg >> 3) + (bid >> 3);
    const int rowTile = (swz / nbx) * 128;
    const int colTile = (swz % nbx) * 128;

    const int wr = wid >> 1, wc = wid & 1;
    const int lrow = lane >> 2, lch = lane & 3;

    f32x4 acc[4][4] = {};

    for (int k0 = 0; k0 < K; k0 += 32){
        __syncthreads();
        #pragma unroll
        for (int cc = 0; cc < 2; ++cc){
            int c = wid*2 + cc;
            int row = c*16 + lrow;
            gload16(A + (size_t)(rowTile + row)*K + k0 + lch*8, (char*)As + c*1024);
            gload16(Bm + (size_t)(colTile + row)*K + k0 + lch*8, (char*)Bs + c*1024);
        }
        __syncthreads();
        bf16x8 af[4], bfr[4];
        #pragma unroll
        for (int mi = 0; mi < 4; ++mi){
            int row = wr*64 + mi*16 + (lane & 15);
            af[mi] = *(const bf16x8*)((const char*)As + row*64 + (lane>>4)*16);
        }
        #pragma unroll
        for (int nj = 0; nj < 4; ++nj){
            int row = wc*64 + nj*16 + (lane & 15);
            bfr[nj] = *(const bf16x8*)((const char*)Bs + row*64 + (lane>>4)*16);
        }
        #pragma unroll
        for (int mi = 0; mi < 4; ++mi)
            #pragma unroll
            for (int nj = 0; nj < 4; ++nj)
                acc[mi][nj] = __builtin_amdgcn_mfma_f32_16x16x32_bf16(af[mi], bfr[nj], acc[mi][nj], 0,0,0);
    }

    #pragma unroll
    for (int mi = 0; mi < 4; ++mi)
        #pragma unroll
        for (int nj = 0; nj < 4; ++nj){
            int row0 = rowTile + wr*64 + mi*16 + (lane>>4)*4;
            int col  = colTile + wc*64 + nj*16 + (lane & 15);
            if (EPI == 0){
                #pragma unroll
                for (int j = 0; j < 4; ++j)
                    Cf[(size_t)(row0+j)*N + col] = acc[mi][nj][j];
            } else {
                int b = row0 >> 11, srow0 = row0 & 2047;
                if (col < 2048){
                    u16* dst = (col < 1024) ? qh : kh;
                    int c2 = col & 1023; int h = c2 >> 6, dh = c2 & 63;
                    size_t base = ((size_t)((b<<4)+h)*2048 + srow0)*64 + dh;
                    #pragma unroll
                    for (int j = 0; j < 4; ++j)
                        dst[base + (size_t)j*64] = f2bf_rne(acc[mi][nj][j]);
                } else {
                    int c2 = col - 2048; int h = c2 >> 6, dh = c2 & 63;
                    union { u16 s[4]; uint2 u; } p;
                    #pragma unroll
                    for (int j = 0; j < 4; ++j) p.s[j] = f2bf_rne(acc[mi][nj][j]);
                    *(uint2*)(vT + ((size_t)((b<<4)+h)*64 + dh)*2048 + srow0) = p.u;
                }
            }
        }
}

// ---------------- Pass A+V: Z[k] = sum_q exp(S*k.q); then vT *= 1/Z in place ----------------
// grid (16 kblocks, 64 heads), 256 thr. Wave w owns k rows [w*32, w*32+32).
// Staging via global_load_lds only (zero register cost — R4's reg-staging spilled).
__global__ __launch_bounds__(256) void k_passAV(
    const u16* __restrict__ qh, const u16* __restrict__ kh, u16* __restrict__ vT)
{
    __shared__ __align__(16) u16 k_lds[128*64];
    __shared__ __align__(16) u16 q_lds[128*64];
    const int lane = threadIdx.x & 63, wid = threadIdx.x >> 6;
    const int kb = blockIdx.x, bh = blockIdx.y;

    // stage k block once (pre-swizzled source, linear LDS dest)
    #pragma unroll
    for (int cc = 0; cc < 4; ++cc){
        int c = wid*4 + cc;
        int row = c*8 + (lane>>3);
        int inner = (lane&7)*16;
        gload16((const char*)(kh + ((size_t)bh*2048 + kb*128 + row)*64) + (inner ^ ((row&7)<<4)),
                (char*)k_lds + c*1024);
    }

    f32x4 sums[2] = {};
    bf16x8 ak[2][2];

    for (int qt = 0; qt < 16; ++qt){
        __syncthreads();   // prior q_lds reads done
        #pragma unroll
        for (int cc = 0; cc < 4; ++cc){
            int c = wid*4 + cc;
            int row = c*8 + (lane>>3);
            int inner = (lane&7)*16;
            gload16((const char*)(qh + ((size_t)bh*2048 + qt*128 + row)*64) + (inner ^ ((row&7)<<4)),
                    (char*)q_lds + c*1024);
        }
        __syncthreads();   // drain
        if (qt == 0){
            #pragma unroll
            for (int mi = 0; mi < 2; ++mi)
                #pragma unroll
                for (int kk = 0; kk < 2; ++kk){
                    int row = wid*32 + mi*16 + (lane & 15);
                    ak[mi][kk] = *(const bf16x8*)((const char*)k_lds + row*128
                                  + ((kk*64 + (lane>>4)*16) ^ ((row&7)<<4)));
                }
        }
        #pragma unroll
        for (int nj = 0; nj < 8; ++nj){
            int row = nj*16 + (lane & 15);
            int base = row*128, sw = (row&7)<<4;
            bf16x8 bq0 = *(const bf16x8*)((const char*)q_lds + base + (((lane>>4)*16) ^ sw));
            bf16x8 bq1 = *(const bf16x8*)((const char*)q_lds + base + ((64 + (lane>>4)*16) ^ sw));
            #pragma unroll
            for (int mi = 0; mi < 2; ++mi){
                f32x4 z = {};
                z = __builtin_amdgcn_mfma_f32_16x16x32_bf16(ak[mi][0], bq0, z, 0,0,0);
                z = __builtin_amdgcn_mfma_f32_16x16x32_bf16(ak[mi][1], bq1, z, 0,0,0);
                #pragma unroll
                for (int j = 0; j < 4; ++j) sums[mi][j] += exp2_hw(z[j] * C2);
            }
        }
    }

    // per-k reciprocal denominators -> LDS (k_lds reused; dead since qt==0)
    float* rz_lds = (float*)k_lds;
    #pragma unroll
    for (int mi = 0; mi < 2; ++mi)
        #pragma unroll
        for (int j = 0; j < 4; ++j){
            float v = sums[mi][j];
            v += __shfl_xor(v, 1); v += __shfl_xor(v, 2);
            v += __shfl_xor(v, 4); v += __shfl_xor(v, 8);
            if ((lane & 15) == 0)
                rz_lds[wid*32 + mi*16 + (lane>>4)*4 + j] = 1.0f / v;
        }

    __syncthreads();   // all waves done computing (q_lds free) + rz writes ordered

    // stage this block's vT stripe [64 d][128 k] into q_lds (linear), scale, write back
    #pragma unroll
    for (int cc = 0; cc < 4; ++cc){
        int c = wid*4 + cc;
        int d = c*4 + (lane>>4);
        gload16(vT + ((size_t)bh*64 + d)*2048 + kb*128 + (lane&15)*8, (char*)q_lds + c*1024);
    }
    __syncthreads();   // drain gload; rz_lds visible

    #pragma unroll
    for (int r = 0; r < 4; ++r){
        int ci = r*256 + threadIdx.x;       // 1024 chunks of 16B
        int d = ci >> 4, c = ci & 15;
        union { uint4 v; unsigned w[4]; } t;
        t.v = *(const uint4*)((const char*)q_lds + d*256 + c*16);
        #pragma unroll
        for (int m = 0; m < 4; ++m){
            float2 rzp = *(const float2*)&rz_lds[c*8 + m*2];
            float lo = __builtin_bit_cast(float, t.w[m] << 16) * rzp.x;
            float hi = __builtin_bit_cast(float, t.w[m] & 0xffff0000u) * rzp.y;
            t.w[m] = pack_bf16_rne(lo, hi);
        }
        *(uint4*)(vT + ((size_t)bh*64 + d)*2048 + kb*128 + c*8) = t.v;
    }
}

// ---------------- Pass B: out[q,d] = sum_k exp(S*q.k) * (v/Z)[k,d] ----------------
// Swapped QK^T -> P assembled into PV A-fragments in-register via permlane swaps.
// Staging via global_load_lds only.
__global__ __launch_bounds__(256) void k_passB(
    const u16* __restrict__ qh, const u16* __restrict__ kh, const u16* __restrict__ vT,
    u16* __restrict__ Zbf)
{
    __shared__ __align__(16) u16 q_lds[128*64];
    __shared__ __align__(16) u16 k_lds[128*64];
    __shared__ __align__(16) u16 v_lds[64*128];
    const int lane = threadIdx.x & 63, wid = threadIdx.x >> 6;
    const int qb = blockIdx.x, bh = blockIdx.y;

    // stage q block once (pre-swizzled source)
    #pragma unroll
    for (int cc = 0; cc < 4; ++cc){
        int c = wid*4 + cc;
        int row = c*8 + (lane>>3);
        int inner = (lane&7)*16;
        gload16((const char*)(qh + ((size_t)bh*2048 + qb*128 + row)*64) + (inner ^ ((row&7)<<4)),
                (char*)q_lds + c*1024);
    }

    f32x4 acc[2][4] = {};
    bf16x8 aq[2][2];

    for (int kt = 0; kt < 16; ++kt){
        __syncthreads();   // prior k_lds/v_lds reads done
        #pragma unroll
        for (int cc = 0; cc < 4; ++cc){
            int c = wid*4 + cc;
            int row = c*8 + (lane>>3);
            int inner = (lane&7)*16;
            gload16((const char*)(kh + ((size_t)bh*2048 + kt*128 + row)*64) + (inner ^ ((row&7)<<4)),
                    (char*)k_lds + c*1024);
        }
        #pragma unroll
        for (int cc = 0; cc < 4; ++cc){
            int c = wid*4 + cc;
            int d = c*4 + (lane>>4);
            int inner = (lane&15)*16;
            gload16((const char*)(vT + ((size_t)bh*64 + d)*2048 + kt*128) + (inner ^ ((d&7)<<4)),
                    (char*)v_lds + c*1024);
        }
        __syncthreads();   // drain
        if (kt == 0){
            #pragma unroll
            for (int mi = 0; mi < 2; ++mi)
                #pragma unroll
                for (int kk = 0; kk < 2; ++kk){
                    int row = wid*32 + mi*16 + (lane & 15);
                    aq[mi][kk] = *(const bf16x8*)((const char*)q_lds + row*128
                                  + ((kk*64 + (lane>>4)*16) ^ ((row&7)<<4)));
                }
        }
        #pragma unroll
        for (int kk = 0; kk < 4; ++kk){
            bf16x8 bv[4];
            #pragma unroll
            for (int nj = 0; nj < 4; ++nj){
                int d = nj*16 + (lane & 15);
                bv[nj] = *(const bf16x8*)((const char*)v_lds + d*256
                           + ((kk*64 + (lane>>4)*16) ^ ((d&7)<<4)));
            }
            bf16x8 bkt[2][2];
            #pragma unroll
            for (int t = 0; t < 2; ++t){
                int row = (kk*2 + t)*16 + (lane & 15);
                int base = row*128, sw = (row&7)<<4;
                bkt[t][0] = *(const bf16x8*)((const char*)k_lds + base + (((lane>>4)*16) ^ sw));
                bkt[t][1] = *(const bf16x8*)((const char*)k_lds + base + ((64 + (lane>>4)*16) ^ sw));
            }
            #pragma unroll
            for (int mi = 0; mi < 2; ++mi){
                f32x4 z0 = {}, z1 = {};
                z0 = __builtin_amdgcn_mfma_f32_16x16x32_bf16(bkt[0][0], aq[mi][0], z0, 0,0,0);
                z0 = __builtin_amdgcn_mfma_f32_16x16x32_bf16(bkt[0][1], aq[mi][1], z0, 0,0,0);
                z1 = __builtin_amdgcn_mfma_f32_16x16x32_bf16(bkt[1][0], aq[mi][0], z1, 0,0,0);
                z1 = __builtin_amdgcn_mfma_f32_16x16x32_bf16(bkt[1][1], aq[mi][1], z1, 0,0,0);
                unsigned u0 = pack_bf16_rne(exp2_hw(z0[0]*C2), exp2_hw(z0[1]*C2));
                unsigned u1 = pack_bf16_rne(exp2_hw(z0[2]*C2), exp2_hw(z0[3]*C2));
                unsigned w0 = pack_bf16_rne(exp2_hw(z1[0]*C2), exp2_hw(z1[1]*C2));
                unsigned w1 = pack_bf16_rne(exp2_hw(z1[2]*C2), exp2_hw(z1[3]*C2));
                plswap32(u0, w0); plswap16(u0, w0);
                plswap32(u1, w1); plswap16(u1, w1);
                union { uint4 ui; bf16x8 v8; } ap;
                ap.ui.x = u0; ap.ui.y = u1; ap.ui.z = w0; ap.ui.w = w1;
                #pragma unroll
                for (int nj = 0; nj < 4; ++nj)
                    acc[mi][nj] = __builtin_amdgcn_mfma_f32_16x16x32_bf16(ap.v8, bv[nj], acc[mi][nj], 0,0,0);
            }
        }
    }

    // epilogue -> merged-head bf16 [b*2048+q][h*64+d]
    const int b = bh >> 4, h = bh & 15;
    #pragma unroll
    for (int mi = 0; mi < 2; ++mi)
        #pragma unroll
        for (int nj = 0; nj < 4; ++nj)
            #pragma unroll
            for (int j = 0; j < 4; ++j){
                int qrow = qb*128 + wid*32 + mi*16 + (lane>>4)*4 + j;
                int d = nj*16 + (lane & 15);
                Zbf[((size_t)b*2048 + qrow)*1024 + h*64 + d] = f2bf_rne(acc[mi][nj][j]);
            }
}

extern "C" void kernel_launch(void* const* d_in, const int* in_sizes, int n_in,
                              void* d_out, int out_size, void* d_ws, size_t ws_size,
                              hipStream_t stream)
{
    const float* x  = (const float*)d_in[0];
    const float* Wq = (const float*)d_in[1];
    const float* Wk = (const float*)d_in[2];
    const float* Wv = (const float*)d_in[3];
    const float* Wo = (const float*)d_in[4];

    char* ws = (char*)d_ws;
    u16*   xbf  = (u16*)ws;                       // 16 MB; reused later as Zbf
    u16*   wqkv = (u16*)(ws + (16u<<20));         //  6 MB
    u16*   wobf = (u16*)(ws + (22u<<20));         //  2 MB
    u16*   vT   = (u16*)(ws + (24u<<20));         // 16 MB [64 bh][64 dh][2048 s]
    u16*   Zbf  = xbf;

    u16* qh = (u16*)d_out;                        // 16 MB [64 bh][2048 s][64 dh]
    u16* kh = (u16*)d_out + (size_t)8192*1024;    // 16 MB

    k_cvt<<<1024, 256, 0, stream>>>(x,  xbf,  8192*1024/8);
    k_cvt<<<256,  256, 0, stream>>>(Wq, wqkv,               1024*1024/8);
    k_cvt<<<256,  256, 0, stream>>>(Wk, wqkv + 1024*1024,   1024*1024/8);
    k_cvt<<<256,  256, 0, stream>>>(Wv, wqkv + 2*1024*1024, 1024*1024/8);
    k_cvt<<<256,  256, 0, stream>>>(Wo, wobf,               1024*1024/8);

    // QKV projection (fused): [8192][1024] x [3072][1024]^T
    k_gemm<1><<<dim3(24, 64), 256, 0, stream>>>(xbf, wqkv, nullptr, qh, kh, vT, 1024, 3072);

    // Pass A: per-key denominators + in-place V scaling
    k_passAV<<<dim3(16, 64), 256, 0, stream>>>(qh, kh, vT);

    // Pass B: fused QK^T -> exp -> PV
    k_passB<<<dim3(16, 64), 256, 0, stream>>>(qh, kh, vT, Zbf);

    // Output projection: [8192][1024] x [1024][1024]^T -> fp32 d_out
    k_gemm<0><<<dim3(8, 64), 256, 0, stream>>>(Zbf, wobf, (float*)d_out,
                                               nullptr, nullptr, nullptr, 1024, 1024);
}

// Round 7
// 351.663 us; speedup vs baseline: 1.4170x; 1.0304x over previous
//
#include <hip/hip_runtime.h>
#include <hip/hip_bf16.h>

#define DEVI __device__ __forceinline__

typedef __attribute__((ext_vector_type(8))) short bf16x8;
typedef __attribute__((ext_vector_type(4))) float f32x4;
typedef unsigned short u16;

static constexpr float SCALE = 0.03125f;             // 1/sqrt(1024)
static constexpr float C2 = 0.045084220045134115f;   // SCALE * log2(e)

// fast RNE f32->bf16 (no NaN path; all values finite here)
DEVI u16 f2bf_rne(float f){
    unsigned t = __builtin_bit_cast(unsigned, f);
    t += 0x7fffu + ((t >> 16) & 1u);
    return (u16)(t >> 16);
}
// RNE pack of two f32 -> u32. NOTE: v_cvt_pk_bf16_f32 is RTZ on gfx950 (R3: coherent -2e-3 bias).
DEVI unsigned pack_bf16_rne(float lo, float hi){
    return (unsigned)f2bf_rne(lo) | ((unsigned)f2bf_rne(hi) << 16);
}
// POSITIVE-ONLY round-half-up pack: +half-ulp on bits, then RTZ cvt_pk == RNE (mod exact ties).
// 3 VALU vs ~14 for pack_bf16_rne. Only valid for lo,hi > 0 (P = exp output).
DEVI unsigned pack_bf16_pos_rhu(float lo, float hi){
    float a = __builtin_bit_cast(float, __builtin_bit_cast(unsigned, lo) + 0x8000u);
    float b = __builtin_bit_cast(float, __builtin_bit_cast(unsigned, hi) + 0x8000u);
    unsigned r;
    asm("v_cvt_pk_bf16_f32 %0, %1, %2" : "=v"(r) : "v"(a), "v"(b));
    return r;
}
DEVI float exp2_hw(float x){
#if defined(__has_builtin) && __has_builtin(__builtin_amdgcn_exp2f)
    return __builtin_amdgcn_exp2f(x);
#else
    return __expf(x * 0.6931471805599453f);
#endif
}

DEVI void gload16(const void* g, void* l){
    __builtin_amdgcn_global_load_lds(
        (const __attribute__((address_space(1))) void*)g,
        (__attribute__((address_space(3))) void*)l,
        16, 0, 0);
}

DEVI void plswap32(unsigned &a, unsigned &b){
#if defined(__has_builtin) && __has_builtin(__builtin_amdgcn_permlane32_swap)
    typedef unsigned uv2 __attribute__((ext_vector_type(2)));
    uv2 r = __builtin_amdgcn_permlane32_swap(a, b, false, false);
    a = r[0]; b = r[1];
#else
    asm("v_permlane32_swap_b32 %0, %1" : "+v"(a), "+v"(b));
#endif
}
DEVI void plswap16(unsigned &a, unsigned &b){
#if defined(__has_builtin) && __has_builtin(__builtin_amdgcn_permlane16_swap)
    typedef unsigned uv2 __attribute__((ext_vector_type(2)));
    uv2 r = __builtin_amdgcn_permlane16_swap(a, b, false, false);
    a = r[0]; b = r[1];
#else
    asm("v_permlane16_swap_b32 %0, %1" : "+v"(a), "+v"(b));
#endif
}

// ---------------- fp32 -> bf16 bulk convert ----------------
__global__ __launch_bounds__(256) void k_cvt(const float* __restrict__ src,
                                             u16* __restrict__ dst, int n8){
    int stride = gridDim.x * blockDim.x;
    for (int i = blockIdx.x * blockDim.x + threadIdx.x; i < n8; i += stride){
        float4 a = *(const float4*)(src + (size_t)i*8);
        float4 b = *(const float4*)(src + (size_t)i*8 + 4);
        uint4 o;
        o.x = pack_bf16_rne(a.x, a.y);
        o.y = pack_bf16_rne(a.z, a.w);
        o.z = pack_bf16_rne(b.x, b.y);
        o.w = pack_bf16_rne(b.z, b.w);
        *(uint4*)(dst + (size_t)i*8) = o;
    }
}

// ---------------- 128x128 NT GEMM, C = A * B^T ----------------
// EPI 0: fp32 store. EPI 1: QKV scatter -> qh (pre-scaled by C2) / kh + vT (transposed, packed).
template<int EPI>
__global__ __launch_bounds__(256) void k_gemm(
    const u16* __restrict__ A, const u16* __restrict__ Bm,
    float* __restrict__ Cf, u16* __restrict__ qh, u16* __restrict__ kh, u16* __restrict__ vT,
    int K, int N)
{
    __shared__ __align__(16) u16 As[128*32];
    __shared__ __align__(16) u16 Bs[128*32];
    const int lane = threadIdx.x & 63, wid = threadIdx.x >> 6;

    const int nbx = gridDim.x;
    const int nwg = nbx * gridDim.y;
    const int bid = blockIdx.y * nbx + blockIdx.x;
    const int swz = (bid & 7) * (nwg >> 3) + (bid >> 3);
    const int rowTile = (swz / nbx) * 128;
    const int colTile = (swz % nbx) * 128;

    const int wr = wid >> 1, wc = wid & 1;
    const int lrow = lane >> 2, lch = lane & 3;

    f32x4 acc[4][4] = {};

    for (int k0 = 0; k0 < K; k0 += 32){
        __syncthreads();
        #pragma unroll
        for (int cc = 0; cc < 2; ++cc){
            int c = wid*2 + cc;
            int row = c*16 + lrow;
            gload16(A + (size_t)(rowTile + row)*K + k0 + lch*8, (char*)As + c*1024);
            gload16(Bm + (size_t)(colTile + row)*K + k0 + lch*8, (char*)Bs + c*1024);
        }
        __syncthreads();
        bf16x8 af[4], bfr[4];
        #pragma unroll
        for (int mi = 0; mi < 4; ++mi){
            int row = wr*64 + mi*16 + (lane & 15);
            af[mi] = *(const bf16x8*)((const char*)As + row*64 + (lane>>4)*16);
        }
        #pragma unroll
        for (int nj = 0; nj < 4; ++nj){
            int row = wc*64 + nj*16 + (lane & 15);
            bfr[nj] = *(const bf16x8*)((const char*)Bs + row*64 + (lane>>4)*16);
        }
        #pragma unroll
        for (int mi = 0; mi < 4; ++mi)
            #pragma unroll
            for (int nj = 0; nj < 4; ++nj)
                acc[mi][nj] = __builtin_amdgcn_mfma_f32_16x16x32_bf16(af[mi], bfr[nj], acc[mi][nj], 0,0,0);
    }

    #pragma unroll
    for (int mi = 0; mi < 4; ++mi)
        #pragma unroll
        for (int nj = 0; nj < 4; ++nj){
            int row0 = rowTile + wr*64 + mi*16 + (lane>>4)*4;
            int col  = colTile + wc*64 + nj*16 + (lane & 15);
            if (EPI == 0){
                #pragma unroll
                for (int j = 0; j < 4; ++j)
                    Cf[(size_t)(row0+j)*N + col] = acc[mi][nj][j];
            } else {
                int b = row0 >> 11, srow0 = row0 & 2047;
                if (col < 2048){
                    // q gets pre-scaled by C2 so attention passes do exp2(z) with no mul
                    bool isq = (col < 1024);
                    u16* dst = isq ? qh : kh;
                    float scl = isq ? C2 : 1.0f;
                    int c2 = col & 1023; int h = c2 >> 6, dh = c2 & 63;
                    size_t base = ((size_t)((b<<4)+h)*2048 + srow0)*64 + dh;
                    #pragma unroll
                    for (int j = 0; j < 4; ++j)
                        dst[base + (size_t)j*64] = f2bf_rne(acc[mi][nj][j] * scl);
                } else {
                    int c2 = col - 2048; int h = c2 >> 6, dh = c2 & 63;
                    union { u16 s[4]; uint2 u; } p;
                    #pragma unroll
                    for (int j = 0; j < 4; ++j) p.s[j] = f2bf_rne(acc[mi][nj][j]);
                    *(uint2*)(vT + ((size_t)((b<<4)+h)*64 + dh)*2048 + srow0) = p.u;
                }
            }
        }
}

// ---------------- Pass A+V: Z[k] = sum_q exp2(k.qC2); then vT *= 1/Z in place ----------------
// grid (16 kblocks, 64 heads), 256 thr. Wave w owns k rows [w*32, w*32+32).
__global__ __launch_bounds__(256) void k_passAV(
    const u16* __restrict__ qh, const u16* __restrict__ kh, u16* __restrict__ vT)
{
    __shared__ __align__(16) u16 k_lds[128*64];
    __shared__ __align__(16) u16 q_lds[128*64];
    const int lane = threadIdx.x & 63, wid = threadIdx.x >> 6;
    const int kb = blockIdx.x, bh = blockIdx.y;

    // stage k block once (pre-swizzled source, linear LDS dest)
    #pragma unroll
    for (int cc = 0; cc < 4; ++cc){
        int c = wid*4 + cc;
        int row = c*8 + (lane>>3);
        int inner = (lane&7)*16;
        gload16((const char*)(kh + ((size_t)bh*2048 + kb*128 + row)*64) + (inner ^ ((row&7)<<4)),
                (char*)k_lds + c*1024);
    }

    f32x4 sums[2] = {};
    bf16x8 ak[2][2];

    for (int qt = 0; qt < 16; ++qt){
        __syncthreads();   // prior q_lds reads done
        #pragma unroll
        for (int cc = 0; cc < 4; ++cc){
            int c = wid*4 + cc;
            int row = c*8 + (lane>>3);
            int inner = (lane&7)*16;
            gload16((const char*)(qh + ((size_t)bh*2048 + qt*128 + row)*64) + (inner ^ ((row&7)<<4)),
                    (char*)q_lds + c*1024);
        }
        __syncthreads();   // drain
        if (qt == 0){
            #pragma unroll
            for (int mi = 0; mi < 2; ++mi)
                #pragma unroll
                for (int kk = 0; kk < 2; ++kk){
                    int row = wid*32 + mi*16 + (lane & 15);
                    ak[mi][kk] = *(const bf16x8*)((const char*)k_lds + row*128
                                  + ((kk*64 + (lane>>4)*16) ^ ((row&7)<<4)));
                }
        }
        #pragma unroll
        for (int nj = 0; nj < 8; ++nj){
            int row = nj*16 + (lane & 15);
            int base = row*128, sw = (row&7)<<4;
            bf16x8 bq0 = *(const bf16x8*)((const char*)q_lds + base + (((lane>>4)*16) ^ sw));
            bf16x8 bq1 = *(const bf16x8*)((const char*)q_lds + base + ((64 + (lane>>4)*16) ^ sw));
            #pragma unroll
            for (int mi = 0; mi < 2; ++mi){
                f32x4 z = {};
                z = __builtin_amdgcn_mfma_f32_16x16x32_bf16(ak[mi][0], bq0, z, 0,0,0);
                z = __builtin_amdgcn_mfma_f32_16x16x32_bf16(ak[mi][1], bq1, z, 0,0,0);
                #pragma unroll
                for (int j = 0; j < 4; ++j) sums[mi][j] += exp2_hw(z[j]);   // q pre-scaled by C2
            }
        }
    }

    // per-k reciprocal denominators -> LDS (k_lds reused; dead since qt==0)
    float* rz_lds = (float*)k_lds;
    #pragma unroll
    for (int mi = 0; mi < 2; ++mi)
        #pragma unroll
        for (int j = 0; j < 4; ++j){
            float v = sums[mi][j];
            v += __shfl_xor(v, 1); v += __shfl_xor(v, 2);
            v += __shfl_xor(v, 4); v += __shfl_xor(v, 8);
            if ((lane & 15) == 0)
                rz_lds[wid*32 + mi*16 + (lane>>4)*4 + j] = 1.0f / v;
        }

    __syncthreads();   // all waves done computing (q_lds free) + rz writes ordered

    // stage this block's vT stripe [64 d][128 k] into q_lds (linear), scale, write back
    #pragma unroll
    for (int cc = 0; cc < 4; ++cc){
        int c = wid*4 + cc;
        int d = c*4 + (lane>>4);
        gload16(vT + ((size_t)bh*64 + d)*2048 + kb*128 + (lane&15)*8, (char*)q_lds + c*1024);
    }
    __syncthreads();   // drain gload; rz_lds visible

    #pragma unroll
    for (int r = 0; r < 4; ++r){
        int ci = r*256 + threadIdx.x;       // 1024 chunks of 16B
        int d = ci >> 4, c = ci & 15;
        union { uint4 v; unsigned w[4]; } t;
        t.v = *(const uint4*)((const char*)q_lds + d*256 + c*16);
        #pragma unroll
        for (int m = 0; m < 4; ++m){
            float2 rzp = *(const float2*)&rz_lds[c*8 + m*2];
            float lo = __builtin_bit_cast(float, t.w[m] << 16) * rzp.x;
            float hi = __builtin_bit_cast(float, t.w[m] & 0xffff0000u) * rzp.y;
            t.w[m] = pack_bf16_rne(lo, hi);   // signed values: keep exact RNE here
        }
        *(uint4*)(vT + ((size_t)bh*64 + d)*2048 + kb*128 + c*8) = t.v;
    }
}

// ---------------- Pass B: out[q,d] = sum_k exp2(qC2.k) * (v/Z)[k,d] ----------------
// Swapped QK^T -> P assembled into PV A-fragments in-register via permlane swaps.
__global__ __launch_bounds__(256) void k_passB(
    const u16* __restrict__ qh, const u16* __restrict__ kh, const u16* __restrict__ vT,
    u16* __restrict__ Zbf)
{
    __shared__ __align__(16) u16 q_lds[128*64];
    __shared__ __align__(16) u16 k_lds[128*64];
    __shared__ __align__(16) u16 v_lds[64*128];
    const int lane = threadIdx.x & 63, wid = threadIdx.x >> 6;
    const int qb = blockIdx.x, bh = blockIdx.y;

    // stage q block once (pre-swizzled source)
    #pragma unroll
    for (int cc = 0; cc < 4; ++cc){
        int c = wid*4 + cc;
        int row = c*8 + (lane>>3);
        int inner = (lane&7)*16;
        gload16((const char*)(qh + ((size_t)bh*2048 + qb*128 + row)*64) + (inner ^ ((row&7)<<4)),
                (char*)q_lds + c*1024);
    }

    f32x4 acc[2][4] = {};
    bf16x8 aq[2][2];

    for (int kt = 0; kt < 16; ++kt){
        __syncthreads();   // prior k_lds/v_lds reads done
        #pragma unroll
        for (int cc = 0; cc < 4; ++cc){
            int c = wid*4 + cc;
            int row = c*8 + (lane>>3);
            int inner = (lane&7)*16;
            gload16((const char*)(kh + ((size_t)bh*2048 + kt*128 + row)*64) + (inner ^ ((row&7)<<4)),
                    (char*)k_lds + c*1024);
        }
        #pragma unroll
        for (int cc = 0; cc < 4; ++cc){
            int c = wid*4 + cc;
            int d = c*4 + (lane>>4);
            int inner = (lane&15)*16;
            gload16((const char*)(vT + ((size_t)bh*64 + d)*2048 + kt*128) + (inner ^ ((d&7)<<4)),
                    (char*)v_lds + c*1024);
        }
        __syncthreads();   // drain
        if (kt == 0){
            #pragma unroll
            for (int mi = 0; mi < 2; ++mi)
                #pragma unroll
                for (int kk = 0; kk < 2; ++kk){
                    int row = wid*32 + mi*16 + (lane & 15);
                    aq[mi][kk] = *(const bf16x8*)((const char*)q_lds + row*128
                                  + ((kk*64 + (lane>>4)*16) ^ ((row&7)<<4)));
                }
        }
        #pragma unroll
        for (int kk = 0; kk < 4; ++kk){
            bf16x8 bv[4];
            #pragma unroll
            for (int nj = 0; nj < 4; ++nj){
                int d = nj*16 + (lane & 15);
                bv[nj] = *(const bf16x8*)((const char*)v_lds + d*256
                           + ((kk*64 + (lane>>4)*16) ^ ((d&7)<<4)));
            }
            bf16x8 bkt[2][2];
            #pragma unroll
            for (int t = 0; t < 2; ++t){
                int row = (kk*2 + t)*16 + (lane & 15);
                int base = row*128, sw = (row&7)<<4;
                bkt[t][0] = *(const bf16x8*)((const char*)k_lds + base + (((lane>>4)*16) ^ sw));
                bkt[t][1] = *(const bf16x8*)((const char*)k_lds + base + ((64 + (lane>>4)*16) ^ sw));
            }
            #pragma unroll
            for (int mi = 0; mi < 2; ++mi){
                f32x4 z0 = {}, z1 = {};
                z0 = __builtin_amdgcn_mfma_f32_16x16x32_bf16(bkt[0][0], aq[mi][0], z0, 0,0,0);
                z0 = __builtin_amdgcn_mfma_f32_16x16x32_bf16(bkt[0][1], aq[mi][1], z0, 0,0,0);
                z1 = __builtin_amdgcn_mfma_f32_16x16x32_bf16(bkt[1][0], aq[mi][0], z1, 0,0,0);
                z1 = __builtin_amdgcn_mfma_f32_16x16x32_bf16(bkt[1][1], aq[mi][1], z1, 0,0,0);
                // q pre-scaled by C2 -> exp2 directly; P>0 -> biased-RTZ pack == RNE
                unsigned u0 = pack_bf16_pos_rhu(exp2_hw(z0[0]), exp2_hw(z0[1]));
                unsigned u1 = pack_bf16_pos_rhu(exp2_hw(z0[2]), exp2_hw(z0[3]));
                unsigned w0 = pack_bf16_pos_rhu(exp2_hw(z1[0]), exp2_hw(z1[1]));
                unsigned w1 = pack_bf16_pos_rhu(exp2_hw(z1[2]), exp2_hw(z1[3]));
                plswap32(u0, w0); plswap16(u0, w0);
                plswap32(u1, w1); plswap16(u1, w1);
                union { uint4 ui; bf16x8 v8; } ap;
                ap.ui.x = u0; ap.ui.y = u1; ap.ui.z = w0; ap.ui.w = w1;
                #pragma unroll
                for (int nj = 0; nj < 4; ++nj)
                    acc[mi][nj] = __builtin_amdgcn_mfma_f32_16x16x32_bf16(ap.v8, bv[nj], acc[mi][nj], 0,0,0);
            }
        }
    }

    // epilogue -> merged-head bf16 [b*2048+q][h*64+d]
    const int b = bh >> 4, h = bh & 15;
    #pragma unroll
    for (int mi = 0; mi < 2; ++mi)
        #pragma unroll
        for (int nj = 0; nj < 4; ++nj)
            #pragma unroll
            for (int j = 0; j < 4; ++j){
                int qrow = qb*128 + wid*32 + mi*16 + (lane>>4)*4 + j;
                int d = nj*16 + (lane & 15);
                Zbf[((size_t)b*2048 + qrow)*1024 + h*64 + d] = f2bf_rne(acc[mi][nj][j]);
            }
}

extern "C" void kernel_launch(void* const* d_in, const int* in_sizes, int n_in,
                              void* d_out, int out_size, void* d_ws, size_t ws_size,
                              hipStream_t stream)
{
    const float* x  = (const float*)d_in[0];
    const float* Wq = (const float*)d_in[1];
    const float* Wk = (const float*)d_in[2];
    const float* Wv = (const float*)d_in[3];
    const float* Wo = (const float*)d_in[4];

    char* ws = (char*)d_ws;
    u16*   xbf  = (u16*)ws;                       // 16 MB; reused later as Zbf
    u16*   wqkv = (u16*)(ws + (16u<<20));         //  6 MB
    u16*   wobf = (u16*)(ws + (22u<<20));         //  2 MB
    u16*   vT   = (u16*)(ws + (24u<<20));         // 16 MB [64 bh][64 dh][2048 s]
    u16*   Zbf  = xbf;

    u16* qh = (u16*)d_out;                        // 16 MB [64 bh][2048 s][64 dh]
    u16* kh = (u16*)d_out + (size_t)8192*1024;    // 16 MB

    k_cvt<<<1024, 256, 0, stream>>>(x,  xbf,  8192*1024/8);
    k_cvt<<<256,  256, 0, stream>>>(Wq, wqkv,               1024*1024/8);
    k_cvt<<<256,  256, 0, stream>>>(Wk, wqkv + 1024*1024,   1024*1024/8);
    k_cvt<<<256,  256, 0, stream>>>(Wv, wqkv + 2*1024*1024, 1024*1024/8);
    k_cvt<<<256,  256, 0, stream>>>(Wo, wobf,               1024*1024/8);

    // QKV projection (fused): [8192][1024] x [3072][1024]^T
    k_gemm<1><<<dim3(24, 64), 256, 0, stream>>>(xbf, wqkv, nullptr, qh, kh, vT, 1024, 3072);

    // Pass A: per-key denominators + in-place V scaling
    k_passAV<<<dim3(16, 64), 256, 0, stream>>>(qh, kh, vT);

    // Pass B: fused QK^T -> exp2 -> PV
    k_passB<<<dim3(16, 64), 256, 0, stream>>>(qh, kh, vT, Zbf);

    // Output projection: [8192][1024] x [1024][1024]^T -> fp32 d_out
    k_gemm<0><<<dim3(8, 64), 256, 0, stream>>>(Zbf, wobf, (float*)d_out,
                                               nullptr, nullptr, nullptr, 1024, 1024);
}